// Round 7
// baseline (846.377 us; speedup 1.0000x reference)
//
#include <hip/hip_runtime.h>

#define NNODES 100000
#define NEDGES 1600000
#define NGRAPH 512
#define EPSBN 1e-5f
#define DEGCAP 64    // max in-degree; Binomial tail beyond 64 ~1e-20
#define NBUCK 512    // dst buckets of 256 nodes (391 used)
#define BSH 8
#define BCAP 4864    // per-bucket capacity: mean 4096, sd 64, +12 sigma margin
#define P1_BLOCKS ((NEDGES + 4095)/4096)   // 391
#define GEMM_BLOCKS ((NNODES + 63)/64)     // 1563

#define SROWS (NNODES + 1)                     // rows per slice incl zero row
#define SLICE_SH ((size_t)SROWS * 16)          // ushorts per 16-channel slice

typedef unsigned short ushort_t;
typedef unsigned int uint_t;

typedef __attribute__((ext_vector_type(8))) __bf16 bf16x8;
typedef __attribute__((ext_vector_type(4))) float f32x4;
typedef __attribute__((ext_vector_type(2))) uint_t uintx2;

__device__ __forceinline__ float b2f(ushort_t u){ return __uint_as_float(((uint_t)u)<<16); }
__device__ __forceinline__ ushort_t f2b(float f){
  union { __bf16 h; ushort_t u; } c;
  c.h = (__bf16)f;
  return c.u;
}
__device__ __forceinline__ uint_t pkbf(float a, float b){
  union { __bf16 h[2]; uint_t u; } c;
  c.h[0] = (__bf16)a; c.h[1] = (__bf16)b;
  return c.u;
}
__device__ __forceinline__ float lo16(uint_t d){ return b2f((ushort_t)(d & 0xffffu)); }
__device__ __forceinline__ float hi16(uint_t d){ return b2f((ushort_t)(d >> 16)); }

// slice-major hs/rbuf addressing: channel c of row v lives at
// (c>>4)*SLICE_SH + v*16 + (c&15)   [ushort units]
__device__ __forceinline__ size_t hoff(int v, int c){
  return (size_t)(c >> 4) * SLICE_SH + (size_t)v * 16 + (c & 15);
}

__device__ __forceinline__ f32x4 mfma_bf16(bf16x8 a, bf16x8 b, f32x4 c){
  return __builtin_amdgcn_mfma_f32_16x16x32_bf16(a, b, c, 0, 0, 0);
}

union Frag8 { ushort_t u[8]; bf16x8 v; };

__device__ __forceinline__ bf16x8 cvt8_f32_bf16(const float* __restrict__ p){
  float4 v0 = *(const float4*)(const void*)p;
  float4 v1 = *(const float4*)(const void*)(p + 4);
  Frag8 f;
  f.u[0] = f2b(v0.x); f.u[1] = f2b(v0.y); f.u[2] = f2b(v0.z); f.u[3] = f2b(v0.w);
  f.u[4] = f2b(v1.x); f.u[5] = f2b(v1.y); f.u[6] = f2b(v1.z); f.u[7] = f2b(v1.w);
  return f.v;
}

// ---- phase 1 (fused): edge bucketing + gstart + GEMM0 (raw bf16 hs0) ----
__global__ __launch_bounds__(256) void k_p1(const int* __restrict__ src,
                                            const int* __restrict__ dst,
                                            int* __restrict__ gBucket,   // stride 16 ints
                                            int2* __restrict__ ebuf,
                                            const int* __restrict__ batch,
                                            int* __restrict__ gstart,
                                            const float* __restrict__ x,
                                            const float* __restrict__ W0,
                                            ushort_t* __restrict__ hs){
  __shared__ __attribute__((aligned(16))) ushort_t sMem[128*136];

  if (blockIdx.x < P1_BLOCKS){
    int* cntL  = (int*)sMem;
    int* baseL = cntL + NBUCK;
    int* ofsL  = baseL + NBUCK;
    int t = threadIdx.x;
    #pragma unroll
    for (int r = 0; r < 2; ++r){
      int i = t + r*256;
      cntL[i] = 0; ofsL[i] = 0;
    }
    __syncthreads();

    int base = blockIdx.x * 4096;
    int e0 = base + t*16;
    int s[16], d[16];
    int ne = 0;
    if (e0 + 16 <= NEDGES){
      #pragma unroll
      for (int q = 0; q < 4; ++q){
        int4 sv = *(const int4*)(src + e0 + q*4);
        int4 dv = *(const int4*)(dst + e0 + q*4);
        s[q*4+0]=sv.x; s[q*4+1]=sv.y; s[q*4+2]=sv.z; s[q*4+3]=sv.w;
        d[q*4+0]=dv.x; d[q*4+1]=dv.y; d[q*4+2]=dv.z; d[q*4+3]=dv.w;
      }
      ne = 16;
    } else {
      for (int e = e0; e < NEDGES && ne < 16; ++e, ++ne){
        s[ne] = src[e]; d[ne] = dst[e];
      }
    }
    for (int k = 0; k < ne; ++k) atomicAdd(&cntL[d[k] >> BSH], 1);
    __syncthreads();
    #pragma unroll
    for (int r = 0; r < 2; ++r){
      int i = t + r*256;
      int c = cntL[i];
      baseL[i] = c ? atomicAdd(&gBucket[i*16], c) : 0;
    }
    __syncthreads();
    for (int k = 0; k < ne; ++k){
      int b = d[k] >> BSH;
      int o = atomicAdd(&ofsL[b], 1);
      ebuf[(size_t)b*BCAP + baseL[b] + o] = make_int2(s[k], d[k]);
    }
    return;
  }
  if (blockIdx.x == P1_BLOCKS){
    #pragma unroll
    for (int r = 0; r < 2; ++r){
      int g = threadIdx.x + r*256;
      int lo = 0, hi = NNODES;
      while (lo < hi){
        int mid = (lo + hi) >> 1;
        if (batch[mid] < g) lo = mid + 1; else hi = mid;
      }
      gstart[g] = lo;
    }
    if (threadIdx.x == 0) gstart[NGRAPH] = NNODES;
    return;
  }

  // ---- GEMM layer 0: hs[slice-major] = bf16( x @ W0 ), un-normalized ----
  ushort_t* sWT = sMem;
  int bb = blockIdx.x - P1_BLOCKS - 1;
  for (int idx = threadIdx.x; idx < 128*128; idx += 256){
    int c = idx >> 7, jj = idx & 127;
    sWT[jj*136 + c] = f2b(W0[idx]);
  }
  __syncthreads();

  int wave = threadIdx.x >> 6;
  int lane = threadIdx.x & 63;
  int quad = lane >> 4;
  int l16  = lane & 15;
  int row0 = bb*64 + wave*16;

  int m  = row0 + l16;
  int mc = (m < NNODES) ? m : (NNODES - 1);

  const float* ap = x + (size_t)mc*128 + quad*8;
  bf16x8 af0 = cvt8_f32_bf16(ap);
  bf16x8 af1 = cvt8_f32_bf16(ap + 32);
  bf16x8 af2 = cvt8_f32_bf16(ap + 64);
  bf16x8 af3 = cvt8_f32_bf16(ap + 96);

  f32x4 acc[8];
  #pragma unroll
  for (int ct = 0; ct < 8; ++ct){
    const ushort_t* bp = sWT + (ct*16 + l16)*136 + quad*8;
    bf16x8 b0 = *(const bf16x8*)(const void*)(bp);
    bf16x8 b1 = *(const bf16x8*)(const void*)(bp + 32);
    bf16x8 b2 = *(const bf16x8*)(const void*)(bp + 64);
    bf16x8 b3 = *(const bf16x8*)(const void*)(bp + 96);
    f32x4 a_ = {0.f, 0.f, 0.f, 0.f};
    a_ = mfma_bf16(af0, b0, a_);
    a_ = mfma_bf16(af1, b1, a_);
    a_ = mfma_bf16(af2, b2, a_);
    a_ = mfma_bf16(af3, b3, a_);
    acc[ct] = a_;
  }

  int rbase = row0 + quad*4;
  #pragma unroll
  for (int ct = 0; ct < 8; ++ct){
    int colc = ct*16 + l16;
    #pragma unroll
    for (int rg = 0; rg < 4; ++rg){
      int rr = rbase + rg;
      if (rr < NNODES) hs[hoff(rr, colc)] = f2b(acc[ct][rg]);
    }
  }
}

// ---- phase 2: per-bucket placement into colx + cnt + pad ----
__global__ __launch_bounds__(256) void k_p2(const int2* __restrict__ ebuf,
                                            const int* __restrict__ gBucket,
                                            int* __restrict__ colx,
                                            int* __restrict__ cnt){
  __shared__ int slotcnt[256];
  int t = threadIdx.x;
  int b = blockIdx.x;
  slotcnt[t] = 0;
  __syncthreads();

  int nb = gBucket[b*16];
  int vbase = b << BSH;

  for (int e = t; e < nb; e += 256){
    int2 p = ebuf[(size_t)b*BCAP + e];
    int slot = atomicAdd(&slotcnt[p.y - vbase], 1);
    colx[p.y*DEGCAP + slot] = p.x;
  }
  __syncthreads();

  int v = vbase + t;
  if (v < NNODES){
    int c = slotcnt[t];
    cnt[v] = c;
    int ce = (c <= 15) ? 15 : 31;
    for (int s = c; s < ce; ++s) colx[(size_t)v*DEGCAP + s] = NNODES;
  }
}

// ---- normalize hs0 in place by rsqrt(cnt+1), slice-major, wide grid ----
#define NORM_BLOCKS 1024
__global__ __launch_bounds__(256) void k_norm(const int* __restrict__ cnt,
                                              ushort_t* __restrict__ hs){
  uintx2* H2 = (uintx2*)hs;
  const size_t SL4 = (size_t)SROWS * 4;   // uintx2 per slice
  for (int j = blockIdx.x*256 + threadIdx.x; j < NNODES*4; j += NORM_BLOCKS*256){
    int v = j >> 2;
    float dv = rsqrtf((float)(cnt[v] + 1));
    #pragma unroll
    for (int s = 0; s < 8; ++s){
      uintx2 d = H2[(size_t)s*SL4 + j];
      d.x = pkbf(lo16(d.x)*dv, hi16(d.x)*dv);
      d.y = pkbf(lo16(d.y)*dv, hi16(d.y)*dv);
      H2[(size_t)s*SL4 + j] = d;
    }
  }
}

// ---- GEMM layers 1,2: hs = bf16( (A @ WT + K) * rsqrt(cnt+1) ), slice-major A and hs ----
__global__ __launch_bounds__(256) void k_gemm(const ushort_t* __restrict__ A,
                                              const ushort_t* __restrict__ WT,
                                              const float* __restrict__ Kv,
                                              const int* __restrict__ cnt,
                                              ushort_t* __restrict__ hs){
  __shared__ __attribute__((aligned(16))) ushort_t sWT[128*136];
  {
    const uint4* sp = (const uint4*)WT;
    uint4* dp = (uint4*)sWT;
    for (int i = threadIdx.x; i < (128*136*2)/16; i += 256) dp[i] = sp[i];
  }
  __syncthreads();

  int wave = threadIdx.x >> 6;
  int lane = threadIdx.x & 63;
  int quad = lane >> 4;
  int l16  = lane & 15;
  int row0 = blockIdx.x*64 + wave*16;

  int m  = row0 + l16;
  int mc = (m < NNODES) ? m : (NNODES - 1);

  int c0 = quad*8;
  bf16x8 af0 = *(const bf16x8*)(const void*)(A + hoff(mc, c0));
  bf16x8 af1 = *(const bf16x8*)(const void*)(A + hoff(mc, c0 + 32));
  bf16x8 af2 = *(const bf16x8*)(const void*)(A + hoff(mc, c0 + 64));
  bf16x8 af3 = *(const bf16x8*)(const void*)(A + hoff(mc, c0 + 96));

  f32x4 acc[8];
  #pragma unroll
  for (int ct = 0; ct < 8; ++ct){
    const ushort_t* bp = sWT + (ct*16 + l16)*136 + quad*8;
    bf16x8 b0 = *(const bf16x8*)(const void*)(bp);
    bf16x8 b1 = *(const bf16x8*)(const void*)(bp + 32);
    bf16x8 b2 = *(const bf16x8*)(const void*)(bp + 64);
    bf16x8 b3 = *(const bf16x8*)(const void*)(bp + 96);
    f32x4 a_ = {0.f, 0.f, 0.f, 0.f};
    a_ = mfma_bf16(af0, b0, a_);
    a_ = mfma_bf16(af1, b1, a_);
    a_ = mfma_bf16(af2, b2, a_);
    a_ = mfma_bf16(af3, b3, a_);
    acc[ct] = a_;
  }

  int rbase = row0 + quad*4;
  float dv[4];
  #pragma unroll
  for (int rg = 0; rg < 4; ++rg){
    int rr = rbase + rg;
    int cc = cnt[(rr < NNODES) ? rr : (NNODES - 1)];
    dv[rg] = rsqrtf((float)(cc + 1));
  }
  #pragma unroll
  for (int ct = 0; ct < 8; ++ct){
    int colc = ct*16 + l16;
    float kv = Kv[colc];
    #pragma unroll
    for (int rg = 0; rg < 4; ++rg){
      int rr = rbase + rg;
      if (rr < NNODES){
        float val = (acc[ct][rg] + kv) * dv[rg];
        hs[hoff(rr, colc)] = f2b(val);
      }
    }
  }
}

// ---- aggregation (phased channel-slices): slice-outer loop over 8 × 3.2MB slices,
//      LDS-cached indices, wave = 16 nodes × 4 lanes × 8B ----
#define AGG_BLOCKS 1024     // exactly all-resident at 4 blocks/CU
#define NPB 98              // nodes per block (1024*98 >= 100000)
#define NHEX 7              // hexadecs (16-node groups) per block

#define FENCE8(A) asm volatile("" :: \
  "v"(A[0]),"v"(A[1]),"v"(A[2]),"v"(A[3]),"v"(A[4]),"v"(A[5]),"v"(A[6]),"v"(A[7]))

template<bool WR>
__global__ __launch_bounds__(256, 4) void k_agg(const ushort_t* __restrict__ hs,
                                                const int* __restrict__ cnt,
                                                const int* __restrict__ colx,
                                                const float* __restrict__ bias,
                                                const int* __restrict__ batch,
                                                ushort_t* __restrict__ rout,
                                                float* __restrict__ poolS,
                                                float* __restrict__ chansum,
                                                float* __restrict__ chansumsq){
  __shared__ int colx_s[NPB*65];       // stride 65 -> conflict-free ds_read
  __shared__ float bsum[128];
  __shared__ float bsq[128];
  __shared__ float poolL[4*128];       // pool buffer for up to 4 graphs in block span

  int tid = threadIdx.x;
  if (tid < 128){ bsum[tid] = 0.f; bsq[tid] = 0.f; }
  #pragma unroll
  for (int r = 0; r < 2; ++r) poolL[tid + r*256] = 0.f;

  int bn0 = blockIdx.x * NPB;
  int rn = NNODES - bn0;
  if (rn > NPB) rn = NPB;
  if (rn < 0) rn = 0;

  for (int i = tid; i < rn*64; i += 256){
    int ln = i >> 6, sl = i & 63;
    colx_s[ln*65 + sl] = colx[(size_t)(bn0 + ln)*64 + sl];
  }
  int gbase = (rn > 0) ? batch[bn0] : 0;
  __syncthreads();

  int wave = tid >> 6;
  int lane = tid & 63;
  int grp = lane >> 2;       // node within hexadec
  int sub = lane & 3;        // 8B chunk (4 channels) within 32B row-slice

  const uintx2* H2 = (const uintx2*)hs;
  uintx2* R2 = (uintx2*)rout;

  for (int s = 0; s < 8; ++s){
    const uintx2* Hs = H2 + (size_t)s*SROWS*4;
    uintx2* Rs = R2 + (size_t)s*SROWS*4;
    float4 bb = *(const float4*)(bias + s*16 + sub*4);
    float ss0=0.f, ss1=0.f, ss2=0.f, ss3=0.f;
    float q0=0.f, q1=0.f, q2=0.f, q3=0.f;

    for (int hx = wave; hx < NHEX; hx += 4){
      if (hx*16 >= rn) break;
      int ln = hx*16 + grp;
      bool valid = (ln < rn);
      int vg = bn0 + ln;
      int cv = 0, g = 0;
      if (valid){ cv = cnt[vg]; g = batch[vg]; }

      // wave-uniform round count
      int mx = cv;
      mx = max(mx, __shfl_xor(mx, 4, 64));
      mx = max(mx, __shfl_xor(mx, 8, 64));
      mx = max(mx, __shfl_xor(mx, 16, 64));
      mx = max(mx, __shfl_xor(mx, 32, 64));
      int rounds = mx + 1;   // round 0 = self, rounds 1..cv = neighbors

      int lnc = (ln < NPB) ? ln : (NPB - 1);
      int lofs = lnc*65;
      float a0=0.f, a1=0.f, a2=0.f, a3=0.f;

      for (int rb = 0; rb < rounds; rb += 8){
        uintx2 gb[8];
        #pragma unroll
        for (int k = 0; k < 8; ++k){
          int r = rb + k;
          int sl = r - 1; if (sl < 0) sl = 0;
          int ui = colx_s[lofs + sl];
          int u = (r == 0) ? (valid ? vg : NNODES)
                           : ((r - 1 < cv) ? ui : NNODES);
          gb[k] = Hs[(size_t)u*4 + sub];
        }
        FENCE8(gb);
        #pragma unroll
        for (int k = 0; k < 8; ++k){
          a0 += lo16(gb[k].x); a1 += hi16(gb[k].x);
          a2 += lo16(gb[k].y); a3 += hi16(gb[k].y);
        }
      }

      float dvv = rsqrtf((float)(cv + 1));
      float r0 = fmaxf(a0*dvv + bb.x, 0.f);
      float r1 = fmaxf(a1*dvv + bb.y, 0.f);
      float r2 = fmaxf(a2*dvv + bb.z, 0.f);
      float r3 = fmaxf(a3*dvv + bb.w, 0.f);

      if (valid){
        if constexpr (WR){
          uintx2 wv;
          wv.x = pkbf(r0, r1);
          wv.y = pkbf(r2, r3);
          Rs[(size_t)vg*4 + sub] = wv;
        }
        ss0 += r0; ss1 += r1; ss2 += r2; ss3 += r3;
        q0 += r0*r0; q1 += r1*r1; q2 += r2*r2; q3 += r3*r3;
        int cb = s*16 + sub*4;
        int gs = g - gbase;
        if (gs >= 0 && gs < 4){
          atomicAdd(&poolL[gs*128 + cb + 0], r0);
          atomicAdd(&poolL[gs*128 + cb + 1], r1);
          atomicAdd(&poolL[gs*128 + cb + 2], r2);
          atomicAdd(&poolL[gs*128 + cb + 3], r3);
        } else {
          atomicAdd(&poolS[(size_t)g*128 + cb + 0], r0);
          atomicAdd(&poolS[(size_t)g*128 + cb + 1], r1);
          atomicAdd(&poolS[(size_t)g*128 + cb + 2], r2);
          atomicAdd(&poolS[(size_t)g*128 + cb + 3], r3);
        }
      }
    }

    int cb = s*16 + sub*4;
    atomicAdd(&bsum[cb + 0], ss0);
    atomicAdd(&bsum[cb + 1], ss1);
    atomicAdd(&bsum[cb + 2], ss2);
    atomicAdd(&bsum[cb + 3], ss3);
    atomicAdd(&bsq[cb + 0], q0);
    atomicAdd(&bsq[cb + 1], q1);
    atomicAdd(&bsq[cb + 2], q2);
    atomicAdd(&bsq[cb + 3], q3);
  }

  __syncthreads();
  if (tid < 128){
    atomicAdd(&chansum[tid],   bsum[tid]);
    atomicAdd(&chansumsq[tid], bsq[tid]);
  }
  for (int i = tid; i < 512; i += 256){
    int gs = i >> 7, c = i & 127;
    float v = poolL[i];
    int g = gbase + gs;
    if (v != 0.f && g < NGRAPH) atomicAdd(&poolS[(size_t)g*128 + c], v);
  }
}

__global__ void k_fold(const float* __restrict__ Wn,
                       const float* __restrict__ chansum, const float* __restrict__ chansumsq,
                       const float* __restrict__ gamma, const float* __restrict__ beta,
                       ushort_t* __restrict__ WT, float* __restrict__ Kv,
                       float* __restrict__ avec, float* __restrict__ cvec){
  __shared__ float red[128];
  int j = blockIdx.x, c = threadIdx.x;
  const float invN = 1.0f / (float)NNODES;
  float mu  = chansum[c] * invN;
  float var = chansumsq[c] * invN - mu*mu;
  float a = gamma[c] * rsqrtf(var + EPSBN);
  float cc = beta[c] - mu*a;
  if (j == 0){ avec[c] = a; cvec[c] = cc; }
  float wv = Wn[c*128 + j];
  WT[j*136 + c] = f2b(a * wv);
  red[c] = cc * wv;
  __syncthreads();
  for (int off = 64; off > 0; off >>= 1){
    if (c < off) red[c] += red[c + off];
    __syncthreads();
  }
  if (c == 0) Kv[j] = red[0];
}

__global__ void k_final(const float* __restrict__ poolS, const int* __restrict__ gstart,
                        const float* __restrict__ avec, const float* __restrict__ cvec,
                        const float* __restrict__ chansum2, const float* __restrict__ chansumsq2,
                        const float* __restrict__ gamma2, const float* __restrict__ beta2,
                        float* __restrict__ out){
  int g = blockIdx.x, c = threadIdx.x;
  float n = (float)(gstart[g + 1] - gstart[g]);
  #pragma unroll
  for (int i = 0; i < 2; ++i){
    float v = avec[i*128 + c] * poolS[((size_t)i*NGRAPH + g)*128 + c] + n * cvec[i*128 + c];
    out[(size_t)g*384 + i*128 + c] = v;
  }
  const float invN = 1.0f / (float)NNODES;
  float mu  = chansum2[c] * invN;
  float var = chansumsq2[c] * invN - mu*mu;
  float a2 = gamma2[c] * rsqrtf(var + EPSBN);
  float c2 = beta2[c] - mu*a2;
  float v2 = a2 * poolS[((size_t)2*NGRAPH + g)*128 + c] + n * c2;
  out[(size_t)g*384 + 2*128 + c] = v2;
}

extern "C" void kernel_launch(void* const* d_in, const int* in_sizes, int n_in,
                              void* d_out, int out_size, void* d_ws, size_t ws_size,
                              hipStream_t stream){
  (void)in_sizes; (void)n_in; (void)out_size; (void)ws_size;

  const float* x     = (const float*)d_in[0];
  const int*   ei    = (const int*)d_in[1];
  const int*   batch = (const int*)d_in[2];
  const float* Wp[3] = {(const float*)d_in[3], (const float*)d_in[7],  (const float*)d_in[11]};
  const float* bp[3] = {(const float*)d_in[4], (const float*)d_in[8],  (const float*)d_in[12]};
  const float* gp[3] = {(const float*)d_in[5], (const float*)d_in[9],  (const float*)d_in[13]};
  const float* tp[3] = {(const float*)d_in[6], (const float*)d_in[10], (const float*)d_in[14]};
  const int* srcp = ei;
  const int* dstp = ei + NEDGES;

  char* w = (char*)d_ws;
  size_t off = 0;
  auto take = [&](size_t bytes) -> char* {
    char* p = w + off;
    off += (bytes + 511) & ~(size_t)511;
    return p;
  };
  int*      cnt       = (int*)take((size_t)NNODES*4);
  int*      colx      = (int*)take((size_t)NNODES*DEGCAP*4);
  int*      gstart    = (int*)take((NGRAPH+1)*4);
  ushort_t* hs        = (ushort_t*)take((size_t)SROWS*128*2);   // 8 slices, zero row each
  ushort_t* rbuf      = (ushort_t*)take((size_t)SROWS*128*2);   // also aliased as ebuf pre-agg0
  ushort_t* WT        = (ushort_t*)take(128*136*2);
  float*    Kv        = (float*)take(128*4);
  float*    chanstats = (float*)take(3*256*4);
  float*    poolS     = (float*)take((size_t)3*NGRAPH*128*4);
  float*    avec      = (float*)take(2*128*4);
  float*    cvec      = (float*)take(2*128*4);
  int*      gBucket   = (int*)take(NBUCK*16*4);

  // ebuf aliases rbuf: ebuf consumed by k_p2 before agg0 first writes rbuf.
  int2* ebuf = (int2*)rbuf;   // needs NBUCK*BCAP*8 = 19.9 MB <= 25.6 MB

  hipMemsetAsync(gBucket,   0, NBUCK*16*4,             stream);
  hipMemsetAsync(poolS,     0, (size_t)3*NGRAPH*128*4, stream);
  hipMemsetAsync(chanstats, 0, 3*256*4,                stream);
  // zero row (index NNODES) per slice, used as gather padding target
  for (int s = 0; s < 8; ++s)
    hipMemsetAsync(hs + (size_t)s*SLICE_SH + (size_t)NNODES*16, 0, 32, stream);

  // phase 1: bucket edges + gstart + GEMM0 (raw hs0, slice-major)
  k_p1<<<P1_BLOCKS + 1 + GEMM_BLOCKS, 256, 0, stream>>>(
      srcp, dstp, gBucket, ebuf, batch, gstart, x, Wp[0], hs);
  // phase 2: place colx, write cnt, pad colx (to 15 or 31)
  k_p2<<<NBUCK, 256, 0, stream>>>(ebuf, gBucket, colx, cnt);
  // wide in-place normalize of hs0 by rsqrt(cnt+1)
  k_norm<<<NORM_BLOCKS, 256, 0, stream>>>(cnt, hs);

  // layer 0
  k_agg<true><<<AGG_BLOCKS, 256, 0, stream>>>(hs, cnt, colx, bp[0], batch, rbuf,
                                              poolS, chanstats, chanstats + 128);
  k_fold<<<128, 128, 0, stream>>>(Wp[1], chanstats, chanstats + 128,
                                  gp[0], tp[0], WT, Kv, avec, cvec);
  // layer 1
  k_gemm<<<GEMM_BLOCKS, 256, 0, stream>>>(rbuf, WT, Kv, cnt, hs);
  k_agg<true><<<AGG_BLOCKS, 256, 0, stream>>>(hs, cnt, colx, bp[1], batch, rbuf,
                                              poolS + (size_t)NGRAPH*128,
                                              chanstats + 256, chanstats + 256 + 128);
  k_fold<<<128, 128, 0, stream>>>(Wp[2], chanstats + 256, chanstats + 256 + 128,
                                  gp[1], tp[1], WT, Kv, avec + 128, cvec + 128);
  // layer 2
  k_gemm<<<GEMM_BLOCKS, 256, 0, stream>>>(rbuf, WT, Kv, cnt, hs);
  k_agg<false><<<AGG_BLOCKS, 256, 0, stream>>>(hs, cnt, colx, bp[2], batch, rbuf,
                                               poolS + (size_t)2*NGRAPH*128,
                                               chanstats + 512, chanstats + 512 + 128);

  k_final<<<NGRAPH, 128, 0, stream>>>(poolS, gstart, avec, cvec,
                                      chanstats + 512, chanstats + 512 + 128,
                                      gp[2], tp[2], (float*)d_out);
}

// Round 8
// 491.896 us; speedup vs baseline: 1.7206x; 1.7206x over previous
//
#include <hip/hip_runtime.h>

#define NNODES 100000
#define NEDGES 1600000
#define NGRAPH 512
#define EPSBN 1e-5f
#define DEGCAP 64    // max in-degree; Binomial tail beyond 64 ~1e-20
#define NBUCK 512    // dst buckets of 256 nodes (391 used)
#define BSH 8
#define BCAP 4864    // per-bucket capacity: mean 4096, sd 64, +12 sigma margin
#define P1_BLOCKS ((NEDGES + 4095)/4096)   // 391
#define GEMM_BLOCKS ((NNODES + 63)/64)     // 1563

typedef unsigned short ushort_t;
typedef unsigned int uint_t;

typedef __attribute__((ext_vector_type(8))) __bf16 bf16x8;
typedef __attribute__((ext_vector_type(4))) float f32x4;
typedef __attribute__((ext_vector_type(2))) uint_t uintx2;
typedef __attribute__((ext_vector_type(2))) int intx2;

__device__ __forceinline__ float b2f(ushort_t u){ return __uint_as_float(((uint_t)u)<<16); }
// native bf16 convert (RNE) — compiler emits v_cvt_pk_bf16_f32
__device__ __forceinline__ ushort_t f2b(float f){
  union { __bf16 h; ushort_t u; } c;
  c.h = (__bf16)f;
  return c.u;
}
__device__ __forceinline__ uint_t pkbf(float a, float b){
  union { __bf16 h[2]; uint_t u; } c;
  c.h[0] = (__bf16)a; c.h[1] = (__bf16)b;
  return c.u;
}
__device__ __forceinline__ float lo16(uint_t d){ return b2f((ushort_t)(d & 0xffffu)); }
__device__ __forceinline__ float hi16(uint_t d){ return b2f((ushort_t)(d >> 16)); }

__device__ __forceinline__ f32x4 mfma_bf16(bf16x8 a, bf16x8 b, f32x4 c){
  return __builtin_amdgcn_mfma_f32_16x16x32_bf16(a, b, c, 0, 0, 0);
}

union Frag8 { ushort_t u[8]; bf16x8 v; };

// x is read exactly once per element -> non-temporal
__device__ __forceinline__ bf16x8 cvt8_f32_bf16_nt(const float* __restrict__ p){
  f32x4 v0 = __builtin_nontemporal_load((const f32x4*)(const void*)p);
  f32x4 v1 = __builtin_nontemporal_load((const f32x4*)(const void*)(p + 4));
  Frag8 f;
  f.u[0] = f2b(v0[0]); f.u[1] = f2b(v0[1]); f.u[2] = f2b(v0[2]); f.u[3] = f2b(v0[3]);
  f.u[4] = f2b(v1[0]); f.u[5] = f2b(v1[1]); f.u[6] = f2b(v1[2]); f.u[7] = f2b(v1[3]);
  return f.v;
}

// ---- phase 1 (fused): edge bucketing + gstart + GEMM0 (raw bf16 hs0) ----
__global__ __launch_bounds__(256) void k_p1(const int* __restrict__ src,
                                            const int* __restrict__ dst,
                                            int* __restrict__ gBucket,   // stride 16 ints
                                            int2* __restrict__ ebuf,
                                            const int* __restrict__ batch,
                                            int* __restrict__ gstart,
                                            const float* __restrict__ x,
                                            const float* __restrict__ W0,
                                            ushort_t* __restrict__ hs){
  __shared__ __attribute__((aligned(16))) ushort_t sMem[128*136];

  if (blockIdx.x < P1_BLOCKS){
    int* cntL  = (int*)sMem;
    int* baseL = cntL + NBUCK;
    int* ofsL  = baseL + NBUCK;
    int t = threadIdx.x;
    #pragma unroll
    for (int r = 0; r < 2; ++r){
      int i = t + r*256;
      cntL[i] = 0; ofsL[i] = 0;
    }
    __syncthreads();

    int base = blockIdx.x * 4096;
    int e0 = base + t*16;
    int s[16], d[16];
    int ne = 0;
    if (e0 + 16 <= NEDGES){
      #pragma unroll
      for (int q = 0; q < 4; ++q){
        int4 sv = *(const int4*)(src + e0 + q*4);
        int4 dv = *(const int4*)(dst + e0 + q*4);
        s[q*4+0]=sv.x; s[q*4+1]=sv.y; s[q*4+2]=sv.z; s[q*4+3]=sv.w;
        d[q*4+0]=dv.x; d[q*4+1]=dv.y; d[q*4+2]=dv.z; d[q*4+3]=dv.w;
      }
      ne = 16;
    } else {
      for (int e = e0; e < NEDGES && ne < 16; ++e, ++ne){
        s[ne] = src[e]; d[ne] = dst[e];
      }
    }
    for (int k = 0; k < ne; ++k) atomicAdd(&cntL[d[k] >> BSH], 1);
    __syncthreads();
    #pragma unroll
    for (int r = 0; r < 2; ++r){
      int i = t + r*256;
      int c = cntL[i];
      baseL[i] = c ? atomicAdd(&gBucket[i*16], c) : 0;
    }
    __syncthreads();
    for (int k = 0; k < ne; ++k){
      int b = d[k] >> BSH;
      int o = atomicAdd(&ofsL[b], 1);
      ebuf[(size_t)b*BCAP + baseL[b] + o] = make_int2(s[k], d[k]);
    }
    return;
  }
  if (blockIdx.x == P1_BLOCKS){
    #pragma unroll
    for (int r = 0; r < 2; ++r){
      int g = threadIdx.x + r*256;
      int lo = 0, hi = NNODES;
      while (lo < hi){
        int mid = (lo + hi) >> 1;
        if (batch[mid] < g) lo = mid + 1; else hi = mid;
      }
      gstart[g] = lo;
    }
    if (threadIdx.x == 0) gstart[NGRAPH] = NNODES;
    return;
  }

  // ---- GEMM layer 0: hs[m][n] = bf16( sum_k x[m][k]*W0[k][n] ), un-normalized ----
  ushort_t* sWT = sMem;
  int bb = blockIdx.x - P1_BLOCKS - 1;
  for (int idx = threadIdx.x; idx < 128*128; idx += 256){
    int c = idx >> 7, jj = idx & 127;
    sWT[jj*136 + c] = f2b(W0[idx]);
  }
  __syncthreads();

  int wave = threadIdx.x >> 6;
  int lane = threadIdx.x & 63;
  int quad = lane >> 4;
  int l16  = lane & 15;
  int row0 = bb*64 + wave*16;

  int m  = row0 + l16;
  int mc = (m < NNODES) ? m : (NNODES - 1);

  const float* ap = x + (size_t)mc*128 + quad*8;
  bf16x8 af0 = cvt8_f32_bf16_nt(ap);
  bf16x8 af1 = cvt8_f32_bf16_nt(ap + 32);
  bf16x8 af2 = cvt8_f32_bf16_nt(ap + 64);
  bf16x8 af3 = cvt8_f32_bf16_nt(ap + 96);

  f32x4 acc[8];
  #pragma unroll
  for (int ct = 0; ct < 8; ++ct){
    const ushort_t* bp = sWT + (ct*16 + l16)*136 + quad*8;
    bf16x8 b0 = *(const bf16x8*)(const void*)(bp);
    bf16x8 b1 = *(const bf16x8*)(const void*)(bp + 32);
    bf16x8 b2 = *(const bf16x8*)(const void*)(bp + 64);
    bf16x8 b3 = *(const bf16x8*)(const void*)(bp + 96);
    f32x4 a_ = {0.f, 0.f, 0.f, 0.f};
    a_ = mfma_bf16(af0, b0, a_);
    a_ = mfma_bf16(af1, b1, a_);
    a_ = mfma_bf16(af2, b2, a_);
    a_ = mfma_bf16(af3, b3, a_);
    acc[ct] = a_;
  }

  int rbase = row0 + quad*4;
  #pragma unroll
  for (int ct = 0; ct < 8; ++ct){
    int colc = ct*16 + l16;
    #pragma unroll
    for (int rg = 0; rg < 4; ++rg){
      int rr = rbase + rg;
      if (rr < NNODES) hs[(size_t)rr*128 + colc] = f2b(acc[ct][rg]);
    }
  }
}

// ---- phase 2: per-bucket placement into colx + cnt + pad ----
// pad rule: slots [c, ce) <- NNODES (zero row); ce = 15 for c<=15, else 31.
__global__ __launch_bounds__(256) void k_p2(const int2* __restrict__ ebuf,
                                            const int* __restrict__ gBucket,
                                            int* __restrict__ colx,
                                            int* __restrict__ cnt){
  __shared__ int slotcnt[256];
  int t = threadIdx.x;
  int b = blockIdx.x;
  slotcnt[t] = 0;
  __syncthreads();

  int nb = gBucket[b*16];
  int vbase = b << BSH;

  const intx2* eb = (const intx2*)ebuf;
  for (int e = t; e < nb; e += 256){
    intx2 p = __builtin_nontemporal_load(&eb[(size_t)b*BCAP + e]);
    int slot = atomicAdd(&slotcnt[p[1] - vbase], 1);
    __builtin_nontemporal_store(p[0], &colx[p[1]*DEGCAP + slot]);
  }
  __syncthreads();

  int v = vbase + t;
  if (v < NNODES){
    int c = slotcnt[t];
    cnt[v] = c;
    int ce = (c <= 15) ? 15 : 31;
    for (int s = c; s < ce; ++s)
      __builtin_nontemporal_store(NNODES, &colx[(size_t)v*DEGCAP + s]);
  }
}

// ---- normalize hs0 in place by rsqrt(cnt+1), wide grid, non-temporal ----
#define NORM_BLOCKS 1024
__global__ __launch_bounds__(256) void k_norm(const int* __restrict__ cnt,
                                              ushort_t* __restrict__ hs){
  uintx2* H2 = (uintx2*)hs;
  const int total = NNODES*32;   // uintx2 elements (8B = 4 channels)
  for (int i = blockIdx.x*256 + threadIdx.x; i < total; i += NORM_BLOCKS*256){
    int v = i >> 5;
    float dv = rsqrtf((float)(cnt[v] + 1));
    uintx2 d = __builtin_nontemporal_load(&H2[i]);
    d.x = pkbf(lo16(d.x)*dv, hi16(d.x)*dv);
    d.y = pkbf(lo16(d.y)*dv, hi16(d.y)*dv);
    __builtin_nontemporal_store(d, &H2[i]);
  }
}

// ---- GEMM layers 1,2: hs[m][n] = bf16( (sum_k A[m][k]*WT[n][k] + K[n]) * rsqrt(cnt[m]+1) ) ----
__global__ __launch_bounds__(256) void k_gemm(const ushort_t* __restrict__ A,
                                              const ushort_t* __restrict__ WT,
                                              const float* __restrict__ Kv,
                                              const int* __restrict__ cnt,
                                              ushort_t* __restrict__ hs){
  __shared__ __attribute__((aligned(16))) ushort_t sWT[128*136];
  {
    const uint4* sp = (const uint4*)WT;
    uint4* dp = (uint4*)sWT;
    for (int i = threadIdx.x; i < (128*136*2)/16; i += 256) dp[i] = sp[i];
  }
  __syncthreads();

  int wave = threadIdx.x >> 6;
  int lane = threadIdx.x & 63;
  int quad = lane >> 4;
  int l16  = lane & 15;
  int row0 = blockIdx.x*64 + wave*16;

  int m  = row0 + l16;
  int mc = (m < NNODES) ? m : (NNODES - 1);

  const ushort_t* ap = A + (size_t)mc*128 + quad*8;
  bf16x8 af0 = __builtin_nontemporal_load((const bf16x8*)(const void*)(ap));
  bf16x8 af1 = __builtin_nontemporal_load((const bf16x8*)(const void*)(ap + 32));
  bf16x8 af2 = __builtin_nontemporal_load((const bf16x8*)(const void*)(ap + 64));
  bf16x8 af3 = __builtin_nontemporal_load((const bf16x8*)(const void*)(ap + 96));

  f32x4 acc[8];
  #pragma unroll
  for (int ct = 0; ct < 8; ++ct){
    const ushort_t* bp = sWT + (ct*16 + l16)*136 + quad*8;
    bf16x8 b0 = *(const bf16x8*)(const void*)(bp);
    bf16x8 b1 = *(const bf16x8*)(const void*)(bp + 32);
    bf16x8 b2 = *(const bf16x8*)(const void*)(bp + 64);
    bf16x8 b3 = *(const bf16x8*)(const void*)(bp + 96);
    f32x4 a_ = {0.f, 0.f, 0.f, 0.f};
    a_ = mfma_bf16(af0, b0, a_);
    a_ = mfma_bf16(af1, b1, a_);
    a_ = mfma_bf16(af2, b2, a_);
    a_ = mfma_bf16(af3, b3, a_);
    acc[ct] = a_;
  }

  int rbase = row0 + quad*4;
  float dv[4];
  #pragma unroll
  for (int rg = 0; rg < 4; ++rg){
    int rr = rbase + rg;
    int cc = cnt[(rr < NNODES) ? rr : (NNODES - 1)];
    dv[rg] = rsqrtf((float)(cc + 1));
  }
  #pragma unroll
  for (int ct = 0; ct < 8; ++ct){
    int colc = ct*16 + l16;
    float kv = Kv[colc];
    #pragma unroll
    for (int rg = 0; rg < 4; ++rg){
      int rr = rbase + rg;
      if (rr < NNODES){
        float val = (acc[ct][rg] + kv) * dv[rg];
        hs[(size_t)rr*128 + colc] = f2b(val);
      }
    }
  }
}

// ---- aggregation: paired-row dwordx2 gathers (2 rows per vmem instruction),
//      2-node software pipeline (R4/R6 structure — best measured: 73.7 us),
//      non-temporal colx loads + rout stores (keep L2 for hs reuse) ----
#define AGG_BLOCKS 1024
#define AGG_WAVES (AGG_BLOCKS*4)   // 4096 waves = 16 waves/CU (proven sweet spot)
#define AGG_CHUNK ((NNODES + AGG_WAVES - 1) / AGG_WAVES)

#define FENCE8(A) asm volatile("" :: \
  "v"(A[0]),"v"(A[1]),"v"(A[2]),"v"(A[3]),"v"(A[4]),"v"(A[5]),"v"(A[6]),"v"(A[7]))

// round-0: pairs (self, c0),(c1,c2),...,(c13,c14)  -> self + slots 0..14
#define ISSUE_R0(dst, cr, vv) do { \
  _Pragma("unroll") \
  for (int k_ = 0; k_ < 8; ++k_){ \
    int uA_ = (k_ == 0) ? (vv) : __builtin_amdgcn_readlane((cr), 2*k_ - 1); \
    int uB_ = __builtin_amdgcn_readlane((cr), 2*k_); \
    int u_  = sel ? uB_ : uA_; \
    (dst)[k_] = H2[(uint_t)u_*32u + m]; \
  } \
} while(0)

// round-1: pairs over slots 15..30
#define ISSUE_R1(dst, cr) do { \
  _Pragma("unroll") \
  for (int k_ = 0; k_ < 8; ++k_){ \
    int uA_ = __builtin_amdgcn_readlane((cr), 15 + 2*k_); \
    int uB_ = __builtin_amdgcn_readlane((cr), 16 + 2*k_); \
    int u_  = sel ? uB_ : uA_; \
    (dst)[k_] = H2[(uint_t)u_*32u + m]; \
  } \
} while(0)

#define CONSUME8(A) do { \
  FENCE8(A); \
  _Pragma("unroll") \
  for (int k_ = 0; k_ < 8; ++k_){ \
    a0 += lo16((A)[k_].x); a1 += hi16((A)[k_].x); \
    a2 += lo16((A)[k_].y); a3 += hi16((A)[k_].y); \
  } \
} while(0)

template<bool WR>
__global__ __launch_bounds__(256, 4) void k_agg(const ushort_t* __restrict__ hs,
                                                const int* __restrict__ cnt,
                                                const int* __restrict__ colx,
                                                const float* __restrict__ bias,
                                                const int* __restrict__ batch,
                                                ushort_t* __restrict__ rout,
                                                float* __restrict__ poolS,
                                                float* __restrict__ chansum,
                                                float* __restrict__ chansumsq){
  __shared__ float bsum[128];
  __shared__ float bsq[128];
  if (threadIdx.x < 128){ bsum[threadIdx.x] = 0.f; bsq[threadIdx.x] = 0.f; }
  __syncthreads();

  int wave = __builtin_amdgcn_readfirstlane((blockIdx.x << 2) + (threadIdx.x >> 6));
  int lane = threadIdx.x & 63;
  int m    = lane & 31;          // uintx2 index within a row (channels 4m..4m+3)
  int sel  = lane >> 5;          // 0: row-A series, 1: row-B series
  int n0 = wave * AGG_CHUNK;
  int n1 = (n0 + AGG_CHUNK < NNODES) ? (n0 + AGG_CHUNK) : NNODES;

  const uintx2* H2 = (const uintx2*)hs;
  uintx2* R2 = (uintx2*)rout;

  float bbv[4];
  #pragma unroll
  for (int i = 0; i < 4; ++i) bbv[i] = bias[4*m + i];
  int chbase = 4*m + 2*sel;

  float ss0 = 0.f, ss1 = 0.f, sq0 = 0.f, sq1 = 0.f;
  float p0 = 0.f, p1 = 0.f;
  int curg = -1;

  if (n0 < n1){
    // ---- prologue: metadata for v0,v0+1; rounds 0(+1) for v0 ----
    int cr0 = __builtin_nontemporal_load(&colx[(size_t)n0*DEGCAP + lane]);
    int cv0 = cnt[n0];
    int cr1 = 0, cv1 = 0;
    if (n0 + 1 < n1){
      cr1 = __builtin_nontemporal_load(&colx[(size_t)(n0+1)*DEGCAP + lane]);
      cv1 = cnt[n0+1];
    }
    uintx2 e0[8], e1[8];
    ISSUE_R0(e0, cr0, n0);
    if (cv0 > 15) ISSUE_R1(e1, cr0);
    else { _Pragma("unroll") for (int k_ = 0; k_ < 8; ++k_) e1[k_] = (uintx2){0u,0u}; }

    for (int v = n0; v < n1; ++v){
      // 1) metadata for v+2
      int v2 = v + 2;
      int cr2 = 0, cv2 = 0;
      if (v2 < n1){
        cr2 = __builtin_nontemporal_load(&colx[(size_t)v2*DEGCAP + lane]);
        cv2 = cnt[v2];
      }

      // 2) issue next node's rounds 0 (+1) — consumed next iteration
      uintx2 f0[8], f1[8];
      bool hasn = (v + 1 < n1);
      if (hasn){
        ISSUE_R0(f0, cr1, v + 1);
        if (cv1 > 15) ISSUE_R1(f1, cr1);
        else { _Pragma("unroll") for (int k_ = 0; k_ < 8; ++k_) f1[k_] = (uintx2){0u,0u}; }
      } else {
        _Pragma("unroll") for (int k_ = 0; k_ < 8; ++k_){ f0[k_] = (uintx2){0u,0u}; f1[k_] = (uintx2){0u,0u}; }
      }

      // group bookkeeping (overlaps with in-flight loads)
      int g = batch[v];
      if (g != curg){
        if (curg >= 0){
          atomicAdd(&poolS[curg*128 + chbase],     p0);
          atomicAdd(&poolS[curg*128 + chbase + 1], p1);
        }
        p0 = 0.f; p1 = 0.f; curg = g;
      }

      float a0 = 0.f, a1 = 0.f, a2 = 0.f, a3 = 0.f;

      // 3) consume current node's in-flight rounds (issued one node ago)
      CONSUME8(e0);
      if (cv0 > 15) CONSUME8(e1);
      if (cv0 > 31){
        // rare (P ~ 1e-4): sequential paired tail over slots 31..cv0-1
        for (int j = 31; j < cv0; j += 2){
          int uA = __builtin_amdgcn_readlane(cr0, j);
          int uB = (j + 1 < cv0) ? __builtin_amdgcn_readlane(cr0, j + 1) : NNODES;
          int u  = sel ? uB : uA;
          uintx2 dd = H2[(uint_t)u*32u + m];
          a0 += lo16(dd.x); a1 += hi16(dd.x);
          a2 += lo16(dd.y); a3 += hi16(dd.y);
        }
      }

      // 4) combine half-wave series: s = lowerA + upperB per channel
      float s0 = a0 + __shfl_xor(a0, 32, 64);
      float s1 = a1 + __shfl_xor(a1, 32, 64);
      float s2 = a2 + __shfl_xor(a2, 32, 64);
      float s3 = a3 + __shfl_xor(a3, 32, 64);

      // 5) epilogue
      float dvv = rsqrtf((float)(cv0 + 1));
      float r0 = fmaxf(s0*dvv + bbv[0], 0.f);
      float r1 = fmaxf(s1*dvv + bbv[1], 0.f);
      float r2 = fmaxf(s2*dvv + bbv[2], 0.f);
      float r3 = fmaxf(s3*dvv + bbv[3], 0.f);
      if constexpr (WR){
        if (lane < 32){
          uintx2 wv;
          wv.x = pkbf(r0, r1);
          wv.y = pkbf(r2, r3);
          __builtin_nontemporal_store(wv, &R2[(uint_t)v*32u + m]);
        }
      }
      float cA = sel ? r2 : r0;
      float cB = sel ? r3 : r1;
      ss0 += cA; ss1 += cB;
      sq0 += cA*cA; sq1 += cB*cB;
      p0 += cA; p1 += cB;

      // 6) rotate pipeline state
      cr0 = cr1; cv0 = cv1;
      cr1 = cr2; cv1 = cv2;
      #pragma unroll
      for (int k_ = 0; k_ < 8; ++k_){ e0[k_] = f0[k_]; e1[k_] = f1[k_]; }
    }
  }

  if (curg >= 0){
    atomicAdd(&poolS[curg*128 + chbase],     p0);
    atomicAdd(&poolS[curg*128 + chbase + 1], p1);
  }
  atomicAdd(&bsum[chbase],     ss0);
  atomicAdd(&bsum[chbase + 1], ss1);
  atomicAdd(&bsq[chbase],      sq0);
  atomicAdd(&bsq[chbase + 1],  sq1);
  __syncthreads();
  if (threadIdx.x < 128){
    atomicAdd(&chansum[threadIdx.x],   bsum[threadIdx.x]);
    atomicAdd(&chansumsq[threadIdx.x], bsq[threadIdx.x]);
  }
}

__global__ void k_fold(const float* __restrict__ Wn,
                       const float* __restrict__ chansum, const float* __restrict__ chansumsq,
                       const float* __restrict__ gamma, const float* __restrict__ beta,
                       ushort_t* __restrict__ WT, float* __restrict__ Kv,
                       float* __restrict__ avec, float* __restrict__ cvec){
  __shared__ float red[128];
  int j = blockIdx.x, c = threadIdx.x;
  const float invN = 1.0f / (float)NNODES;
  float mu  = chansum[c] * invN;
  float var = chansumsq[c] * invN - mu*mu;
  float a = gamma[c] * rsqrtf(var + EPSBN);
  float cc = beta[c] - mu*a;
  if (j == 0){ avec[c] = a; cvec[c] = cc; }
  float wv = Wn[c*128 + j];
  WT[j*136 + c] = f2b(a * wv);
  red[c] = cc * wv;
  __syncthreads();
  for (int off = 64; off > 0; off >>= 1){
    if (c < off) red[c] += red[c + off];
    __syncthreads();
  }
  if (c == 0) Kv[j] = red[0];
}

__global__ void k_final(const float* __restrict__ poolS, const int* __restrict__ gstart,
                        const float* __restrict__ avec, const float* __restrict__ cvec,
                        const float* __restrict__ chansum2, const float* __restrict__ chansumsq2,
                        const float* __restrict__ gamma2, const float* __restrict__ beta2,
                        float* __restrict__ out){
  int g = blockIdx.x, c = threadIdx.x;
  float n = (float)(gstart[g + 1] - gstart[g]);
  #pragma unroll
  for (int i = 0; i < 2; ++i){
    float v = avec[i*128 + c] * poolS[((size_t)i*NGRAPH + g)*128 + c] + n * cvec[i*128 + c];
    out[(size_t)g*384 + i*128 + c] = v;
  }
  const float invN = 1.0f / (float)NNODES;
  float mu  = chansum2[c] * invN;
  float var = chansumsq2[c] * invN - mu*mu;
  float a2 = gamma2[c] * rsqrtf(var + EPSBN);
  float c2 = beta2[c] - mu*a2;
  float v2 = a2 * poolS[((size_t)2*NGRAPH + g)*128 + c] + n * c2;
  out[(size_t)g*384 + 2*128 + c] = v2;
}

extern "C" void kernel_launch(void* const* d_in, const int* in_sizes, int n_in,
                              void* d_out, int out_size, void* d_ws, size_t ws_size,
                              hipStream_t stream){
  (void)in_sizes; (void)n_in; (void)out_size; (void)ws_size;

  const float* x     = (const float*)d_in[0];
  const int*   ei    = (const int*)d_in[1];
  const int*   batch = (const int*)d_in[2];
  const float* Wp[3] = {(const float*)d_in[3], (const float*)d_in[7],  (const float*)d_in[11]};
  const float* bp[3] = {(const float*)d_in[4], (const float*)d_in[8],  (const float*)d_in[12]};
  const float* gp[3] = {(const float*)d_in[5], (const float*)d_in[9],  (const float*)d_in[13]};
  const float* tp[3] = {(const float*)d_in[6], (const float*)d_in[10], (const float*)d_in[14]};
  const int* srcp = ei;
  const int* dstp = ei + NEDGES;

  char* w = (char*)d_ws;
  size_t off = 0;
  auto take = [&](size_t bytes) -> char* {
    char* p = w + off;
    off += (bytes + 511) & ~(size_t)511;
    return p;
  };
  int*      cnt       = (int*)take((size_t)NNODES*4);
  int*      colx      = (int*)take((size_t)NNODES*DEGCAP*4);
  int*      gstart    = (int*)take((NGRAPH+1)*4);
  ushort_t* hs        = (ushort_t*)take((size_t)(NNODES+1)*128*2);  // +1 zero row for gather padding
  ushort_t* rbuf      = (ushort_t*)take((size_t)NNODES*128*2);   // also aliased as ebuf pre-agg0
  ushort_t* WT        = (ushort_t*)take(128*136*2);
  float*    Kv        = (float*)take(128*4);
  float*    chanstats = (float*)take(3*256*4);
  float*    poolS     = (float*)take((size_t)3*NGRAPH*128*4);
  float*    avec      = (float*)take(2*128*4);
  float*    cvec      = (float*)take(2*128*4);
  int*      gBucket   = (int*)take(NBUCK*16*4);

  // ebuf aliases rbuf: ebuf consumed by k_p2 before agg0 first writes rbuf.
  int2* ebuf = (int2*)rbuf;   // needs NBUCK*BCAP*8 = 19.9 MB <= 25.6 MB

  hipMemsetAsync(gBucket,   0, NBUCK*16*4,             stream);
  hipMemsetAsync(poolS,     0, (size_t)3*NGRAPH*128*4, stream);
  hipMemsetAsync(chanstats, 0, 3*256*4,                stream);
  // zero row (index NNODES) used as gather padding target; k_p1/k_gemm never touch it
  hipMemsetAsync(hs + (size_t)NNODES*128, 0, 128*2,    stream);

  // phase 1: bucket edges + gstart + GEMM0 (raw hs0)
  k_p1<<<P1_BLOCKS + 1 + GEMM_BLOCKS, 256, 0, stream>>>(
      srcp, dstp, gBucket, ebuf, batch, gstart, x, Wp[0], hs);
  // phase 2: place colx, write cnt, pad colx (to 15 or 31)
  k_p2<<<NBUCK, 256, 0, stream>>>(ebuf, gBucket, colx, cnt);
  // wide in-place normalize of hs0 by rsqrt(cnt+1)
  k_norm<<<NORM_BLOCKS, 256, 0, stream>>>(cnt, hs);

  // layer 0
  k_agg<true><<<AGG_BLOCKS, 256, 0, stream>>>(hs, cnt, colx, bp[0], batch, rbuf,
                                              poolS, chanstats, chanstats + 128);
  k_fold<<<128, 128, 0, stream>>>(Wp[1], chanstats, chanstats + 128,
                                  gp[0], tp[0], WT, Kv, avec, cvec);
  // layer 1
  k_gemm<<<GEMM_BLOCKS, 256, 0, stream>>>(rbuf, WT, Kv, cnt, hs);
  k_agg<true><<<AGG_BLOCKS, 256, 0, stream>>>(hs, cnt, colx, bp[1], batch, rbuf,
                                              poolS + (size_t)NGRAPH*128,
                                              chanstats + 256, chanstats + 256 + 128);
  k_fold<<<128, 128, 0, stream>>>(Wp[2], chanstats + 256, chanstats + 256 + 128,
                                  gp[1], tp[1], WT, Kv, avec + 128, cvec + 128);
  // layer 2
  k_gemm<<<GEMM_BLOCKS, 256, 0, stream>>>(rbuf, WT, Kv, cnt, hs);
  k_agg<false><<<AGG_BLOCKS, 256, 0, stream>>>(hs, cnt, colx, bp[2], batch, rbuf,
                                               poolS + (size_t)2*NGRAPH*128,
                                               chanstats + 512, chanstats + 512 + 128);

  k_final<<<NGRAPH, 128, 0, stream>>>(poolS, gstart, avec, cvec,
                                      chanstats + 512, chanstats + 512 + 128,
                                      gp[2], tp[2], (float*)d_out);
}

// Round 9
// 441.931 us; speedup vs baseline: 1.9152x; 1.1131x over previous
//
#include <hip/hip_runtime.h>

#define NNODES 100000
#define NEDGES 1600000
#define NGRAPH 512
#define EPSBN 1e-5f
#define DEGCAP 64    // max in-degree; Binomial tail beyond 64 ~1e-20
#define NBUCK 512    // dst buckets of 256 nodes (391 used)
#define BSH 8
#define BCAP 4864    // per-bucket capacity: mean 4096, sd 64, +12 sigma margin
#define P1_BLOCKS ((NEDGES + 4095)/4096)   // 391
#define GEMM_BLOCKS ((NNODES + 63)/64)     // 1563

typedef unsigned short ushort_t;
typedef unsigned int uint_t;

typedef __attribute__((ext_vector_type(8))) __bf16 bf16x8;
typedef __attribute__((ext_vector_type(4))) float f32x4;
typedef __attribute__((ext_vector_type(2))) uint_t uintx2;

__device__ __forceinline__ float b2f(ushort_t u){ return __uint_as_float(((uint_t)u)<<16); }
// native bf16 convert (RNE) — compiler emits v_cvt_pk_bf16_f32
__device__ __forceinline__ ushort_t f2b(float f){
  union { __bf16 h; ushort_t u; } c;
  c.h = (__bf16)f;
  return c.u;
}
__device__ __forceinline__ uint_t pkbf(float a, float b){
  union { __bf16 h[2]; uint_t u; } c;
  c.h[0] = (__bf16)a; c.h[1] = (__bf16)b;
  return c.u;
}
__device__ __forceinline__ float lo16(uint_t d){ return b2f((ushort_t)(d & 0xffffu)); }
__device__ __forceinline__ float hi16(uint_t d){ return b2f((ushort_t)(d >> 16)); }

__device__ __forceinline__ f32x4 mfma_bf16(bf16x8 a, bf16x8 b, f32x4 c){
  return __builtin_amdgcn_mfma_f32_16x16x32_bf16(a, b, c, 0, 0, 0);
}

union Frag8 { ushort_t u[8]; bf16x8 v; };

__device__ __forceinline__ bf16x8 cvt8_f32_bf16(const float* __restrict__ p){
  float4 v0 = *(const float4*)(const void*)p;
  float4 v1 = *(const float4*)(const void*)(p + 4);
  Frag8 f;
  f.u[0] = f2b(v0.x); f.u[1] = f2b(v0.y); f.u[2] = f2b(v0.z); f.u[3] = f2b(v0.w);
  f.u[4] = f2b(v1.x); f.u[5] = f2b(v1.y); f.u[6] = f2b(v1.z); f.u[7] = f2b(v1.w);
  return f.v;
}

// ---- phase 1: edge bucketing + gstart (GEMM0 moved to k_gemm0, post-cnt) ----
__global__ __launch_bounds__(256) void k_p1(const int* __restrict__ src,
                                            const int* __restrict__ dst,
                                            int* __restrict__ gBucket,   // stride 16 ints
                                            int2* __restrict__ ebuf,
                                            const int* __restrict__ batch,
                                            int* __restrict__ gstart){
  __shared__ int sMem[NBUCK*3];

  if (blockIdx.x < P1_BLOCKS){
    int* cntL  = sMem;
    int* baseL = cntL + NBUCK;
    int* ofsL  = baseL + NBUCK;
    int t = threadIdx.x;
    #pragma unroll
    for (int r = 0; r < 2; ++r){
      int i = t + r*256;
      cntL[i] = 0; ofsL[i] = 0;
    }
    __syncthreads();

    int base = blockIdx.x * 4096;
    int e0 = base + t*16;
    int s[16], d[16];
    int ne = 0;
    if (e0 + 16 <= NEDGES){
      #pragma unroll
      for (int q = 0; q < 4; ++q){
        int4 sv = *(const int4*)(src + e0 + q*4);
        int4 dv = *(const int4*)(dst + e0 + q*4);
        s[q*4+0]=sv.x; s[q*4+1]=sv.y; s[q*4+2]=sv.z; s[q*4+3]=sv.w;
        d[q*4+0]=dv.x; d[q*4+1]=dv.y; d[q*4+2]=dv.z; d[q*4+3]=dv.w;
      }
      ne = 16;
    } else {
      for (int e = e0; e < NEDGES && ne < 16; ++e, ++ne){
        s[ne] = src[e]; d[ne] = dst[e];
      }
    }
    for (int k = 0; k < ne; ++k) atomicAdd(&cntL[d[k] >> BSH], 1);
    __syncthreads();
    #pragma unroll
    for (int r = 0; r < 2; ++r){
      int i = t + r*256;
      int c = cntL[i];
      baseL[i] = c ? atomicAdd(&gBucket[i*16], c) : 0;
    }
    __syncthreads();
    for (int k = 0; k < ne; ++k){
      int b = d[k] >> BSH;
      int o = atomicAdd(&ofsL[b], 1);
      ebuf[(size_t)b*BCAP + baseL[b] + o] = make_int2(s[k], d[k]);
    }
    return;
  }
  // blockIdx.x == P1_BLOCKS: gstart via binary search
  #pragma unroll
  for (int r = 0; r < 2; ++r){
    int g = threadIdx.x + r*256;
    int lo = 0, hi = NNODES;
    while (lo < hi){
      int mid = (lo + hi) >> 1;
      if (batch[mid] < g) lo = mid + 1; else hi = mid;
    }
    gstart[g] = lo;
  }
  if (threadIdx.x == 0) gstart[NGRAPH] = NNODES;
}

// ---- phase 2: per-bucket placement into colx + cnt + pad ----
// pad rule: slots [c, ce) <- NNODES (zero row); ce = 15 for c<=15, else 31.
__global__ __launch_bounds__(256) void k_p2(const int2* __restrict__ ebuf,
                                            const int* __restrict__ gBucket,
                                            int* __restrict__ colx,
                                            int* __restrict__ cnt){
  __shared__ int slotcnt[256];
  int t = threadIdx.x;
  int b = blockIdx.x;
  slotcnt[t] = 0;
  __syncthreads();

  int nb = gBucket[b*16];
  int vbase = b << BSH;

  for (int e = t; e < nb; e += 256){
    int2 p = ebuf[(size_t)b*BCAP + e];
    int slot = atomicAdd(&slotcnt[p.y - vbase], 1);
    colx[p.y*DEGCAP + slot] = p.x;
  }
  __syncthreads();

  int v = vbase + t;
  if (v < NNODES){
    int c = slotcnt[t];
    cnt[v] = c;
    int ce = (c <= 15) ? 15 : 31;
    for (int s = c; s < ce; ++s) colx[(size_t)v*DEGCAP + s] = NNODES;
  }
}

// ---- GEMM layer 0: hs[m][n] = bf16( (sum_k x[m][k]*W0[k][n]) * rsqrt(cnt[m]+1) ) ----
// normalization folded into epilogue (cnt available post-k_p2) — k_norm eliminated.
__global__ __launch_bounds__(256) void k_gemm0(const float* __restrict__ x,
                                               const float* __restrict__ W0,
                                               const int* __restrict__ cnt,
                                               ushort_t* __restrict__ hs){
  __shared__ __attribute__((aligned(16))) ushort_t sWT[128*136];
  for (int idx = threadIdx.x; idx < 128*128; idx += 256){
    int c = idx >> 7, jj = idx & 127;
    sWT[jj*136 + c] = f2b(W0[idx]);
  }
  __syncthreads();

  int wave = threadIdx.x >> 6;
  int lane = threadIdx.x & 63;
  int quad = lane >> 4;
  int l16  = lane & 15;
  int row0 = blockIdx.x*64 + wave*16;

  int m  = row0 + l16;
  int mc = (m < NNODES) ? m : (NNODES - 1);

  const float* ap = x + (size_t)mc*128 + quad*8;
  bf16x8 af0 = cvt8_f32_bf16(ap);
  bf16x8 af1 = cvt8_f32_bf16(ap + 32);
  bf16x8 af2 = cvt8_f32_bf16(ap + 64);
  bf16x8 af3 = cvt8_f32_bf16(ap + 96);

  f32x4 acc[8];
  #pragma unroll
  for (int ct = 0; ct < 8; ++ct){
    const ushort_t* bp = sWT + (ct*16 + l16)*136 + quad*8;
    bf16x8 b0 = *(const bf16x8*)(const void*)(bp);
    bf16x8 b1 = *(const bf16x8*)(const void*)(bp + 32);
    bf16x8 b2 = *(const bf16x8*)(const void*)(bp + 64);
    bf16x8 b3 = *(const bf16x8*)(const void*)(bp + 96);
    f32x4 a_ = {0.f, 0.f, 0.f, 0.f};
    a_ = mfma_bf16(af0, b0, a_);
    a_ = mfma_bf16(af1, b1, a_);
    a_ = mfma_bf16(af2, b2, a_);
    a_ = mfma_bf16(af3, b3, a_);
    acc[ct] = a_;
  }

  int rbase = row0 + quad*4;
  float dv[4];
  #pragma unroll
  for (int rg = 0; rg < 4; ++rg){
    int rr = rbase + rg;
    int cc = cnt[(rr < NNODES) ? rr : (NNODES - 1)];
    dv[rg] = rsqrtf((float)(cc + 1));
  }
  #pragma unroll
  for (int ct = 0; ct < 8; ++ct){
    int colc = ct*16 + l16;
    #pragma unroll
    for (int rg = 0; rg < 4; ++rg){
      int rr = rbase + rg;
      if (rr < NNODES) hs[(size_t)rr*128 + colc] = f2b(acc[ct][rg] * dv[rg]);
    }
  }
}

// ---- GEMM layers 1,2: hs[m][n] = bf16( (sum_k A[m][k]*WT[n][k] + K[n]) * rsqrt(cnt[m]+1) ) ----
__global__ __launch_bounds__(256) void k_gemm(const ushort_t* __restrict__ A,
                                              const ushort_t* __restrict__ WT,
                                              const float* __restrict__ Kv,
                                              const int* __restrict__ cnt,
                                              ushort_t* __restrict__ hs){
  __shared__ __attribute__((aligned(16))) ushort_t sWT[128*136];
  {
    const uint4* sp = (const uint4*)WT;
    uint4* dp = (uint4*)sWT;
    for (int i = threadIdx.x; i < (128*136*2)/16; i += 256) dp[i] = sp[i];
  }
  __syncthreads();

  int wave = threadIdx.x >> 6;
  int lane = threadIdx.x & 63;
  int quad = lane >> 4;
  int l16  = lane & 15;
  int row0 = blockIdx.x*64 + wave*16;

  int m  = row0 + l16;
  int mc = (m < NNODES) ? m : (NNODES - 1);

  const ushort_t* ap = A + (size_t)mc*128 + quad*8;
  bf16x8 af0 = *(const bf16x8*)(const void*)(ap);
  bf16x8 af1 = *(const bf16x8*)(const void*)(ap + 32);
  bf16x8 af2 = *(const bf16x8*)(const void*)(ap + 64);
  bf16x8 af3 = *(const bf16x8*)(const void*)(ap + 96);

  f32x4 acc[8];
  #pragma unroll
  for (int ct = 0; ct < 8; ++ct){
    const ushort_t* bp = sWT + (ct*16 + l16)*136 + quad*8;
    bf16x8 b0 = *(const bf16x8*)(const void*)(bp);
    bf16x8 b1 = *(const bf16x8*)(const void*)(bp + 32);
    bf16x8 b2 = *(const bf16x8*)(const void*)(bp + 64);
    bf16x8 b3 = *(const bf16x8*)(const void*)(bp + 96);
    f32x4 a_ = {0.f, 0.f, 0.f, 0.f};
    a_ = mfma_bf16(af0, b0, a_);
    a_ = mfma_bf16(af1, b1, a_);
    a_ = mfma_bf16(af2, b2, a_);
    a_ = mfma_bf16(af3, b3, a_);
    acc[ct] = a_;
  }

  int rbase = row0 + quad*4;
  float dv[4];
  #pragma unroll
  for (int rg = 0; rg < 4; ++rg){
    int rr = rbase + rg;
    int cc = cnt[(rr < NNODES) ? rr : (NNODES - 1)];
    dv[rg] = rsqrtf((float)(cc + 1));
  }
  #pragma unroll
  for (int ct = 0; ct < 8; ++ct){
    int colc = ct*16 + l16;
    float kv = Kv[colc];
    #pragma unroll
    for (int rg = 0; rg < 4; ++rg){
      int rr = rbase + rg;
      if (rr < NNODES){
        float val = (acc[ct][rg] + kv) * dv[rg];
        hs[(size_t)rr*128 + colc] = f2b(val);
      }
    }
  }
}

// ---- aggregation: paired-row dwordx2 gathers (2 rows per vmem instruction),
//      2-node software pipeline (R4/R6 structure — best measured: 73.7 us) ----
#define AGG_BLOCKS 1024
#define AGG_WAVES (AGG_BLOCKS*4)   // 4096 waves = 16 waves/CU (proven sweet spot)
#define AGG_CHUNK ((NNODES + AGG_WAVES - 1) / AGG_WAVES)

#define FENCE8(A) asm volatile("" :: \
  "v"(A[0]),"v"(A[1]),"v"(A[2]),"v"(A[3]),"v"(A[4]),"v"(A[5]),"v"(A[6]),"v"(A[7]))

// round-0: pairs (self, c0),(c1,c2),...,(c13,c14)  -> self + slots 0..14
#define ISSUE_R0(dst, cr, vv) do { \
  _Pragma("unroll") \
  for (int k_ = 0; k_ < 8; ++k_){ \
    int uA_ = (k_ == 0) ? (vv) : __builtin_amdgcn_readlane((cr), 2*k_ - 1); \
    int uB_ = __builtin_amdgcn_readlane((cr), 2*k_); \
    int u_  = sel ? uB_ : uA_; \
    (dst)[k_] = H2[(uint_t)u_*32u + m]; \
  } \
} while(0)

// round-1: pairs over slots 15..30
#define ISSUE_R1(dst, cr) do { \
  _Pragma("unroll") \
  for (int k_ = 0; k_ < 8; ++k_){ \
    int uA_ = __builtin_amdgcn_readlane((cr), 15 + 2*k_); \
    int uB_ = __builtin_amdgcn_readlane((cr), 16 + 2*k_); \
    int u_  = sel ? uB_ : uA_; \
    (dst)[k_] = H2[(uint_t)u_*32u + m]; \
  } \
} while(0)

#define CONSUME8(A) do { \
  FENCE8(A); \
  _Pragma("unroll") \
  for (int k_ = 0; k_ < 8; ++k_){ \
    a0 += lo16((A)[k_].x); a1 += hi16((A)[k_].x); \
    a2 += lo16((A)[k_].y); a3 += hi16((A)[k_].y); \
  } \
} while(0)

template<bool WR>
__global__ __launch_bounds__(256, 4) void k_agg(const ushort_t* __restrict__ hs,
                                                const int* __restrict__ cnt,
                                                const int* __restrict__ colx,
                                                const float* __restrict__ bias,
                                                const int* __restrict__ batch,
                                                ushort_t* __restrict__ rout,
                                                float* __restrict__ poolS,
                                                float* __restrict__ chansum,
                                                float* __restrict__ chansumsq){
  __shared__ float bsum[128];
  __shared__ float bsq[128];
  if (threadIdx.x < 128){ bsum[threadIdx.x] = 0.f; bsq[threadIdx.x] = 0.f; }
  __syncthreads();

  int wave = __builtin_amdgcn_readfirstlane((blockIdx.x << 2) + (threadIdx.x >> 6));
  int lane = threadIdx.x & 63;
  int m    = lane & 31;          // uintx2 index within a row (channels 4m..4m+3)
  int sel  = lane >> 5;          // 0: row-A series, 1: row-B series
  int n0 = wave * AGG_CHUNK;
  int n1 = (n0 + AGG_CHUNK < NNODES) ? (n0 + AGG_CHUNK) : NNODES;

  const uintx2* H2 = (const uintx2*)hs;
  uintx2* R2 = (uintx2*)rout;

  float bbv[4];
  #pragma unroll
  for (int i = 0; i < 4; ++i) bbv[i] = bias[4*m + i];
  int chbase = 4*m + 2*sel;

  float ss0 = 0.f, ss1 = 0.f, sq0 = 0.f, sq1 = 0.f;
  float p0 = 0.f, p1 = 0.f;
  int curg = -1;

  if (n0 < n1){
    // ---- prologue: metadata for v0,v0+1; rounds 0(+1) for v0 ----
    int cr0 = colx[(size_t)n0*DEGCAP + lane];
    int cv0 = cnt[n0];
    int cr1 = 0, cv1 = 0;
    if (n0 + 1 < n1){
      cr1 = colx[(size_t)(n0+1)*DEGCAP + lane];
      cv1 = cnt[n0+1];
    }
    uintx2 e0[8], e1[8];
    ISSUE_R0(e0, cr0, n0);
    if (cv0 > 15) ISSUE_R1(e1, cr0);
    else { _Pragma("unroll") for (int k_ = 0; k_ < 8; ++k_) e1[k_] = (uintx2){0u,0u}; }

    for (int v = n0; v < n1; ++v){
      // 1) metadata for v+2
      int v2 = v + 2;
      int cr2 = 0, cv2 = 0;
      if (v2 < n1){
        cr2 = colx[(size_t)v2*DEGCAP + lane];
        cv2 = cnt[v2];
      }

      // 2) issue next node's rounds 0 (+1) — consumed next iteration
      uintx2 f0[8], f1[8];
      bool hasn = (v + 1 < n1);
      if (hasn){
        ISSUE_R0(f0, cr1, v + 1);
        if (cv1 > 15) ISSUE_R1(f1, cr1);
        else { _Pragma("unroll") for (int k_ = 0; k_ < 8; ++k_) f1[k_] = (uintx2){0u,0u}; }
      } else {
        _Pragma("unroll") for (int k_ = 0; k_ < 8; ++k_){ f0[k_] = (uintx2){0u,0u}; f1[k_] = (uintx2){0u,0u}; }
      }

      // group bookkeeping (overlaps with in-flight loads)
      int g = batch[v];
      if (g != curg){
        if (curg >= 0){
          atomicAdd(&poolS[curg*128 + chbase],     p0);
          atomicAdd(&poolS[curg*128 + chbase + 1], p1);
        }
        p0 = 0.f; p1 = 0.f; curg = g;
      }

      float a0 = 0.f, a1 = 0.f, a2 = 0.f, a3 = 0.f;

      // 3) consume current node's in-flight rounds (issued one node ago)
      CONSUME8(e0);
      if (cv0 > 15) CONSUME8(e1);
      if (cv0 > 31){
        // rare (P ~ 1e-4): sequential paired tail over slots 31..cv0-1
        for (int j = 31; j < cv0; j += 2){
          int uA = __builtin_amdgcn_readlane(cr0, j);
          int uB = (j + 1 < cv0) ? __builtin_amdgcn_readlane(cr0, j + 1) : NNODES;
          int u  = sel ? uB : uA;
          uintx2 dd = H2[(uint_t)u*32u + m];
          a0 += lo16(dd.x); a1 += hi16(dd.x);
          a2 += lo16(dd.y); a3 += hi16(dd.y);
        }
      }

      // 4) combine half-wave series: s = lowerA + upperB per channel
      float s0 = a0 + __shfl_xor(a0, 32, 64);
      float s1 = a1 + __shfl_xor(a1, 32, 64);
      float s2 = a2 + __shfl_xor(a2, 32, 64);
      float s3 = a3 + __shfl_xor(a3, 32, 64);

      // 5) epilogue
      float dvv = rsqrtf((float)(cv0 + 1));
      float r0 = fmaxf(s0*dvv + bbv[0], 0.f);
      float r1 = fmaxf(s1*dvv + bbv[1], 0.f);
      float r2 = fmaxf(s2*dvv + bbv[2], 0.f);
      float r3 = fmaxf(s3*dvv + bbv[3], 0.f);
      if constexpr (WR){
        if (lane < 32){
          uintx2 wv;
          wv.x = pkbf(r0, r1);
          wv.y = pkbf(r2, r3);
          R2[(uint_t)v*32u + m] = wv;
        }
      }
      float cA = sel ? r2 : r0;
      float cB = sel ? r3 : r1;
      ss0 += cA; ss1 += cB;
      sq0 += cA*cA; sq1 += cB*cB;
      p0 += cA; p1 += cB;

      // 6) rotate pipeline state
      cr0 = cr1; cv0 = cv1;
      cr1 = cr2; cv1 = cv2;
      #pragma unroll
      for (int k_ = 0; k_ < 8; ++k_){ e0[k_] = f0[k_]; e1[k_] = f1[k_]; }
    }
  }

  if (curg >= 0){
    atomicAdd(&poolS[curg*128 + chbase],     p0);
    atomicAdd(&poolS[curg*128 + chbase + 1], p1);
  }
  atomicAdd(&bsum[chbase],     ss0);
  atomicAdd(&bsum[chbase + 1], ss1);
  atomicAdd(&bsq[chbase],      sq0);
  atomicAdd(&bsq[chbase + 1],  sq1);
  __syncthreads();
  if (threadIdx.x < 128){
    atomicAdd(&chansum[threadIdx.x],   bsum[threadIdx.x]);
    atomicAdd(&chansumsq[threadIdx.x], bsq[threadIdx.x]);
  }
}

__global__ void k_fold(const float* __restrict__ Wn,
                       const float* __restrict__ chansum, const float* __restrict__ chansumsq,
                       const float* __restrict__ gamma, const float* __restrict__ beta,
                       ushort_t* __restrict__ WT, float* __restrict__ Kv,
                       float* __restrict__ avec, float* __restrict__ cvec){
  __shared__ float red[128];
  int j = blockIdx.x, c = threadIdx.x;
  const float invN = 1.0f / (float)NNODES;
  float mu  = chansum[c] * invN;
  float var = chansumsq[c] * invN - mu*mu;
  float a = gamma[c] * rsqrtf(var + EPSBN);
  float cc = beta[c] - mu*a;
  if (j == 0){ avec[c] = a; cvec[c] = cc; }
  float wv = Wn[c*128 + j];
  WT[j*136 + c] = f2b(a * wv);
  red[c] = cc * wv;
  __syncthreads();
  for (int off = 64; off > 0; off >>= 1){
    if (c < off) red[c] += red[c + off];
    __syncthreads();
  }
  if (c == 0) Kv[j] = red[0];
}

__global__ void k_final(const float* __restrict__ poolS, const int* __restrict__ gstart,
                        const float* __restrict__ avec, const float* __restrict__ cvec,
                        const float* __restrict__ chansum2, const float* __restrict__ chansumsq2,
                        const float* __restrict__ gamma2, const float* __restrict__ beta2,
                        float* __restrict__ out){
  int g = blockIdx.x, c = threadIdx.x;
  float n = (float)(gstart[g + 1] - gstart[g]);
  #pragma unroll
  for (int i = 0; i < 2; ++i){
    float v = avec[i*128 + c] * poolS[((size_t)i*NGRAPH + g)*128 + c] + n * cvec[i*128 + c];
    out[(size_t)g*384 + i*128 + c] = v;
  }
  const float invN = 1.0f / (float)NNODES;
  float mu  = chansum2[c] * invN;
  float var = chansumsq2[c] * invN - mu*mu;
  float a2 = gamma2[c] * rsqrtf(var + EPSBN);
  float c2 = beta2[c] - mu*a2;
  float v2 = a2 * poolS[((size_t)2*NGRAPH + g)*128 + c] + n * c2;
  out[(size_t)g*384 + 2*128 + c] = v2;
}

extern "C" void kernel_launch(void* const* d_in, const int* in_sizes, int n_in,
                              void* d_out, int out_size, void* d_ws, size_t ws_size,
                              hipStream_t stream){
  (void)in_sizes; (void)n_in; (void)out_size; (void)ws_size;

  const float* x     = (const float*)d_in[0];
  const int*   ei    = (const int*)d_in[1];
  const int*   batch = (const int*)d_in[2];
  const float* Wp[3] = {(const float*)d_in[3], (const float*)d_in[7],  (const float*)d_in[11]};
  const float* bp[3] = {(const float*)d_in[4], (const float*)d_in[8],  (const float*)d_in[12]};
  const float* gp[3] = {(const float*)d_in[5], (const float*)d_in[9],  (const float*)d_in[13]};
  const float* tp[3] = {(const float*)d_in[6], (const float*)d_in[10], (const float*)d_in[14]};
  const int* srcp = ei;
  const int* dstp = ei + NEDGES;

  char* w = (char*)d_ws;
  size_t off = 0;
  auto take = [&](size_t bytes) -> char* {
    char* p = w + off;
    off += (bytes + 511) & ~(size_t)511;
    return p;
  };
  int*      cnt       = (int*)take((size_t)NNODES*4);
  int*      colx      = (int*)take((size_t)NNODES*DEGCAP*4);
  int*      gstart    = (int*)take((NGRAPH+1)*4);
  ushort_t* hs        = (ushort_t*)take((size_t)(NNODES+1)*128*2);  // +1 zero row for gather padding
  ushort_t* rbuf      = (ushort_t*)take((size_t)NNODES*128*2);   // also aliased as ebuf pre-agg0
  ushort_t* WT        = (ushort_t*)take(128*136*2);
  float*    Kv        = (float*)take(128*4);
  float*    chanstats = (float*)take(3*256*4);
  float*    poolS     = (float*)take((size_t)3*NGRAPH*128*4);
  float*    avec      = (float*)take(2*128*4);
  float*    cvec      = (float*)take(2*128*4);
  int*      gBucket   = (int*)take(NBUCK*16*4);

  // ebuf aliases rbuf: ebuf consumed by k_p2 before agg0 first writes rbuf.
  int2* ebuf = (int2*)rbuf;   // needs NBUCK*BCAP*8 = 19.9 MB <= 25.6 MB

  hipMemsetAsync(gBucket,   0, NBUCK*16*4,             stream);
  hipMemsetAsync(poolS,     0, (size_t)3*NGRAPH*128*4, stream);
  hipMemsetAsync(chanstats, 0, 3*256*4,                stream);
  // zero row (index NNODES) used as gather padding target; k_gemm0/k_gemm never touch it
  hipMemsetAsync(hs + (size_t)NNODES*128, 0, 128*2,    stream);

  // phase 1: bucket edges + gstart
  k_p1<<<P1_BLOCKS + 1, 256, 0, stream>>>(srcp, dstp, gBucket, ebuf, batch, gstart);
  // phase 2: place colx, write cnt, pad colx (to 15 or 31)
  k_p2<<<NBUCK, 256, 0, stream>>>(ebuf, gBucket, colx, cnt);
  // GEMM0 with normalization folded into epilogue (k_norm eliminated)
  k_gemm0<<<GEMM_BLOCKS, 256, 0, stream>>>(x, Wp[0], cnt, hs);

  // layer 0
  k_agg<true><<<AGG_BLOCKS, 256, 0, stream>>>(hs, cnt, colx, bp[0], batch, rbuf,
                                              poolS, chanstats, chanstats + 128);
  k_fold<<<128, 128, 0, stream>>>(Wp[1], chanstats, chanstats + 128,
                                  gp[0], tp[0], WT, Kv, avec, cvec);
  // layer 1
  k_gemm<<<GEMM_BLOCKS, 256, 0, stream>>>(rbuf, WT, Kv, cnt, hs);
  k_agg<true><<<AGG_BLOCKS, 256, 0, stream>>>(hs, cnt, colx, bp[1], batch, rbuf,
                                              poolS + (size_t)NGRAPH*128,
                                              chanstats + 256, chanstats + 256 + 128);
  k_fold<<<128, 128, 0, stream>>>(Wp[2], chanstats + 256, chanstats + 256 + 128,
                                  gp[1], tp[1], WT, Kv, avec + 128, cvec + 128);
  // layer 2
  k_gemm<<<GEMM_BLOCKS, 256, 0, stream>>>(rbuf, WT, Kv, cnt, hs);
  k_agg<false><<<AGG_BLOCKS, 256, 0, stream>>>(hs, cnt, colx, bp[2], batch, rbuf,
                                               poolS + (size_t)2*NGRAPH*128,
                                               chanstats + 512, chanstats + 512 + 128);

  k_final<<<NGRAPH, 128, 0, stream>>>(poolS, gstart, avec, cvec,
                                      chanstats + 512, chanstats + 512 + 128,
                                      gp[2], tp[2], (float*)d_out);
}